// Round 6
// baseline (421.426 us; speedup 1.0000x reference)
//
#include <hip/hip_runtime.h>

typedef unsigned short u16;
typedef __attribute__((ext_vector_type(8))) short short8;
typedef __attribute__((ext_vector_type(4))) float f32x4;

#define MFMA(a, b, c) __builtin_amdgcn_mfma_f32_16x16x32_bf16((a), (b), (c), 0, 0, 0)

__device__ inline float bf2f(u16 u) {
  union { unsigned int i; float f; } w; w.i = ((unsigned int)u) << 16; return w.f;
}
__device__ inline u16 f2bf(float x) {
  union { float f; unsigned int i; } u; u.f = x;
  unsigned int r = u.i + 0x7fffu + ((u.i >> 16) & 1u);  // RNE
  return (u16)(r >> 16);
}
__device__ inline unsigned int pk2(float a, float b) {
  return (unsigned int)f2bf(a) | ((unsigned int)f2bf(b) << 16);
}
__device__ inline void unpack8(uint4 v, float* f) {
  union { unsigned int i; float g; } c;
  c.i = v.x << 16;          f[0] = c.g;
  c.i = v.x & 0xffff0000u;  f[1] = c.g;
  c.i = v.y << 16;          f[2] = c.g;
  c.i = v.y & 0xffff0000u;  f[3] = c.g;
  c.i = v.z << 16;          f[4] = c.g;
  c.i = v.z & 0xffff0000u;  f[5] = c.g;
  c.i = v.w << 16;          f[6] = c.g;
  c.i = v.w & 0xffff0000u;  f[7] = c.g;
}

// ---------------- workspace layout (bytes) ----------------
static const size_t SZ_QKV = (size_t)48 * 1024 * 64 * 2;     // 6,291,456
static const size_t SZ_MAP = (size_t)48 * 1024 * 1024 * 2;   // 100,663,296
static const size_t OFF_Q  = 0;
static const size_t OFF_K  = OFF_Q + SZ_QKV;
static const size_t OFF_VT = OFF_K + SZ_QKV;
static const size_t OFF_S  = OFF_VT + SZ_QKV;                // S bf16; DEAD after conv -> U aliases
static const size_t OFF_UG = OFF_S;                          // U f32 [4][48][1024][64] partials (aliases S)
static const size_t OFF_QM = OFF_S + SZ_MAP;                 // Qmix = mixed (N*P-1) bf16 [48 bo][1024][1024]
static const size_t OFF_OT = OFF_QM + SZ_MAP;                // o_tmp [B,N,C] bf16
static const size_t OFF_ST = OFF_OT + SZ_QKV;                // stats 48*2 f32
static const size_t OFF_CS = OFF_ST + 896;                   // colsum_v 48*64 f32
static const size_t OFF_AD = OFF_CS + 12288;                 // addend 48*64 f32
static const size_t OFF_AL = OFF_AD + 12288;                 // alpha 48 f32

static const size_t U_ELEMS = (size_t)48 * 1024 * 64;        // one partial-U, f32 elems

// ---------------- K1: qkv = x @ w_qkv^T, scatter to q,k,vT + fused colsum ----------------
__global__ __launch_bounds__(256, 3) void k_qkv(const float* __restrict__ x,
                                                const float* __restrict__ w,
                                                u16* __restrict__ qb,
                                                u16* __restrict__ kb,
                                                u16* __restrict__ vT,
                                                float* __restrict__ colsum) {
  __shared__ u16 SH[16384];          // As | Bs ; reused as epilogue staging
  u16* As = SH;
  u16* Bs = SH + 8192;
  const int t = threadIdx.x;
  const int m0 = blockIdx.x * 128;
  const int n0 = blockIdx.y * 128;
  const int wave = t >> 6, lane = t & 63;
  const int wm = (wave & 1) * 64, wn = (wave >> 1) * 64;
  const int fr = lane & 15;
  const int fk = (lane >> 4) * 8;
  f32x4 acc[4][4] = {};
  for (int k0 = 0; k0 < 384; k0 += 64) {
#pragma unroll
    for (int i = 0; i < 4; ++i) {
      int e = (i * 256 + t) * 8;
      int row = e >> 6, col = e & 63;
      const float* xp = &x[(size_t)(m0 + row) * 384 + k0 + col];
      const float* wp = &w[(size_t)(n0 + row) * 384 + k0 + col];
      float4 a0 = *(const float4*)xp, a1 = *(const float4*)(xp + 4);
      uint4 av; av.x = pk2(a0.x, a0.y); av.y = pk2(a0.z, a0.w);
      av.z = pk2(a1.x, a1.y); av.w = pk2(a1.z, a1.w);
      *(uint4*)&As[e] = av;
      float4 b0 = *(const float4*)wp, b1 = *(const float4*)(wp + 4);
      uint4 bv; bv.x = pk2(b0.x, b0.y); bv.y = pk2(b0.z, b0.w);
      bv.z = pk2(b1.x, b1.y); bv.w = pk2(b1.z, b1.w);
      *(uint4*)&Bs[e] = bv;
    }
    __syncthreads();
#pragma unroll
    for (int ks = 0; ks < 2; ++ks) {
      const int ko = ks * 32 + fk;
      short8 a[4], b[4];
#pragma unroll
      for (int mi = 0; mi < 4; ++mi) a[mi] = *(const short8*)&As[(wm + mi * 16 + fr) * 64 + ko];
#pragma unroll
      for (int ni = 0; ni < 4; ++ni) b[ni] = *(const short8*)&Bs[(wn + ni * 16 + fr) * 64 + ko];
#pragma unroll
      for (int mi = 0; mi < 4; ++mi)
#pragma unroll
        for (int ni = 0; ni < 4; ++ni) acc[mi][ni] = MFMA(a[mi], b[ni], acc[mi][ni]);
    }
    __syncthreads();
  }
  // ---- epilogue: per-wave LDS transpose, then full-line uint4 stores
  u16* st = &SH[wave * 4096];
  const int gcb = n0 + wn;                 // 64-aligned -> single (s,h) per wave
  const int s = gcb / 384;
  const int remb = gcb - s * 384;
  const int h = remb >> 6;
#pragma unroll
  for (int mi = 0; mi < 4; ++mi)
#pragma unroll
    for (int ni = 0; ni < 4; ++ni)
#pragma unroll
      for (int r = 0; r < 4; ++r) {
        int rl = mi * 16 + (lane >> 4) * 4 + r;   // n-local 0..63
        int cl = ni * 16 + fr;                    // d-local 0..63
        u16 val = f2bf(acc[mi][ni][r]);
        if (s == 2) st[cl * 64 + rl] = val;       // transpose for vT
        else        st[rl * 64 + cl] = val;
      }
  const int gm0 = m0 + wm;                 // 64-aligned
  const int b_ = gm0 >> 10;
  const size_t base = (size_t)(b_ * 6 + h) << 16;
  const int nloc = gm0 & 1023;
  const int r8 = lane >> 3, c8 = (lane & 7) * 8;
#pragma unroll
  for (int i = 0; i < 8; ++i) {
    int lrow = i * 8 + r8;
    uint4 v = *(const uint4*)&st[lrow * 64 + c8];
    if (s == 0)      *(uint4*)&qb[base + (size_t)(nloc + lrow) * 64 + c8] = v;
    else if (s == 1) *(uint4*)&kb[base + (size_t)(nloc + lrow) * 64 + c8] = v;
    else             *(uint4*)&vT[base + (size_t)lrow * 1024 + nloc + c8] = v;
  }
  // ---- fused colsum: s==2 waves reduce their 64n x 64d v-tile over n
  if (s == 2) {
#pragma unroll
    for (int ni = 0; ni < 4; ++ni) {
      float p = 0.f;
#pragma unroll
      for (int mi = 0; mi < 4; ++mi)
#pragma unroll
        for (int r = 0; r < 4; ++r) p += bf2f(f2bf(acc[mi][ni][r]));
      p += __shfl_xor(p, 16, 64);
      p += __shfl_xor(p, 32, 64);
      if ((lane >> 4) == 0)
        atomicAdd(&colsum[(b_ * 6 + h) * 64 + ni * 16 + fr], p);
    }
  }
}

// ---------------- K2a: S = (q @ k^T) * SCALE (coalesced epilogue) ----------------
__global__ __launch_bounds__(256, 3) void k_qk(const u16* __restrict__ qb,
                                               const u16* __restrict__ kb,
                                               u16* __restrict__ S) {
  __shared__ u16 SH[16384];
  u16* As = SH;
  u16* Bs = SH + 8192;
  const int t = threadIdx.x;
  const int m0 = blockIdx.x * 128, n0 = blockIdx.y * 128;
  const int bh = blockIdx.z;
  const u16* A = qb + ((size_t)bh << 16);
  const u16* Bp = kb + ((size_t)bh << 16);
  const int wave = t >> 6, lane = t & 63;
  const int wm = (wave & 1) * 64, wn = (wave >> 1) * 64;
  const int fr = lane & 15;
  const int fk = (lane >> 4) * 8;
  f32x4 acc[4][4] = {};
#pragma unroll
  for (int i = 0; i < 4; ++i) {
    int e = (i * 256 + t) * 8;
    *(uint4*)&As[e] = *(const uint4*)&A[(size_t)m0 * 64 + e];
    *(uint4*)&Bs[e] = *(const uint4*)&Bp[(size_t)n0 * 64 + e];
  }
  __syncthreads();
#pragma unroll
  for (int ks = 0; ks < 2; ++ks) {
    const int ko = ks * 32 + fk;
    short8 a[4], b[4];
#pragma unroll
    for (int mi = 0; mi < 4; ++mi) a[mi] = *(const short8*)&As[(wm + mi * 16 + fr) * 64 + ko];
#pragma unroll
    for (int ni = 0; ni < 4; ++ni) b[ni] = *(const short8*)&Bs[(wn + ni * 16 + fr) * 64 + ko];
#pragma unroll
    for (int mi = 0; mi < 4; ++mi)
#pragma unroll
      for (int ni = 0; ni < 4; ++ni) acc[mi][ni] = MFMA(a[mi], b[ni], acc[mi][ni]);
  }
  __syncthreads();                        // all waves done reading As/Bs
  u16* st = &SH[wave * 4096];
#pragma unroll
  for (int mi = 0; mi < 4; ++mi)
#pragma unroll
    for (int ni = 0; ni < 4; ++ni)
#pragma unroll
      for (int r = 0; r < 4; ++r)
        st[(mi * 16 + (lane >> 4) * 4 + r) * 64 + ni * 16 + fr] = f2bf(acc[mi][ni][r] * 0.125f);
  const size_t sb = (size_t)bh << 20;
  const int grow0 = m0 + wm, gcol0 = n0 + wn;
  const int r8 = lane >> 3, c8 = (lane & 7) * 8;
#pragma unroll
  for (int i = 0; i < 8; ++i) {
    int lrow = i * 8 + r8;
    uint4 v = *(const uint4*)&st[lrow * 64 + c8];
    *(uint4*)&S[sb + (size_t)(grow0 + lrow) * 1024 + gcol0 + c8] = v;
  }
}

// ---------------- K2b: depthwise 3x3 conv + softmax + HEAD MIX ----------------
__global__ __launch_bounds__(256, 3) void k_conv_softmax_mix(const u16* __restrict__ S,
                                                             const float* __restrict__ w_kq,
                                                             const float* __restrict__ wh,
                                                             u16* __restrict__ Qb) {
  __shared__ u16 Sr[24 * 1040];      // [h*4 + i][1040], i = input row (n0-1+i)
  __shared__ float redA[4], redB[4];
  const int t = threadIdx.x;
  const int b = blockIdx.y;
  const int n0 = blockIdx.x * 2;
  if (t < 24) { Sr[t * 1040 + 7] = 0; Sr[t * 1040 + 1032] = 0; }
#pragma unroll
  for (int c = 0; c < 12; ++c) {
    int lid = c * 256 + t;           // 0..3071
    int hrow = lid >> 7;             // 0..23
    int col8 = (lid & 127) * 8;
    int h = hrow >> 2, i = hrow & 3;
    int g = n0 - 1 + i;
    uint4 val = make_uint4(0u, 0u, 0u, 0u);
    if (g >= 0 && g < 1024)
      val = *(const uint4*)&S[(((size_t)(b * 6 + h)) << 20) + (size_t)g * 1024 + col8];
    *(uint4*)&Sr[hrow * 1040 + 8 + col8] = val;
  }
  __syncthreads();
  const int row = t >> 7;            // 0..1 (output row within block)
  const int wave = t >> 6;
  const int lane = t & 63;
  const int m0 = (t & 127) * 8;
  const int n = n0 + row;
  float mix[6][8];
#pragma unroll
  for (int o = 0; o < 6; ++o)
#pragma unroll
    for (int j = 0; j < 8; ++j) mix[o][j] = 0.f;
  for (int h = 0; h < 6; ++h) {
    float wv[9];
#pragma unroll
    for (int i = 0; i < 9; ++i) wv[i] = w_kq[h * 9 + i];
    float o8[8] = {0.f, 0.f, 0.f, 0.f, 0.f, 0.f, 0.f, 0.f};
#pragma unroll
    for (int i = 0; i < 3; ++i) {
      const u16* rowp = &Sr[(h * 4 + row + i) * 1040 + 8];
      float left = bf2f(rowp[m0 - 1]);
      float md[8];
      unpack8(*(const uint4*)&rowp[m0], md);
      float right = bf2f(rowp[m0 + 8]);
      float w0 = wv[i * 3 + 0], w1 = wv[i * 3 + 1], w2 = wv[i * 3 + 2];
      o8[0] += w0 * left + w1 * md[0] + w2 * md[1];
#pragma unroll
      for (int j = 1; j < 7; ++j) o8[j] += w0 * md[j - 1] + w1 * md[j] + w2 * md[j + 1];
      o8[7] += w0 * md[6] + w1 * md[7] + w2 * right;
    }
    float mx = o8[0];
#pragma unroll
    for (int j = 1; j < 8; ++j) mx = fmaxf(mx, o8[j]);
    for (int off = 32; off; off >>= 1) mx = fmaxf(mx, __shfl_xor(mx, off, 64));
    if (lane == 0) redA[wave] = mx;
    __syncthreads();
    float rmax = fmaxf(redA[row * 2], redA[row * 2 + 1]);
    float e8[8], s = 0.f;
#pragma unroll
    for (int j = 0; j < 8; ++j) { e8[j] = __expf(o8[j] - rmax); s += e8[j]; }
    for (int off = 32; off; off >>= 1) s += __shfl_xor(s, off, 64);
    if (lane == 0) redB[wave] = s;
    __syncthreads();
    float rsum = redB[row * 2] + redB[row * 2 + 1];
    float scale = 1024.f / rsum;
    const float w0h = wh[0 * 6 + h], w1h = wh[1 * 6 + h], w2h = wh[2 * 6 + h],
                w3h = wh[3 * 6 + h], w4h = wh[4 * 6 + h], w5h = wh[5 * 6 + h];
#pragma unroll
    for (int j = 0; j < 8; ++j) {
      float p = e8[j] * scale - 1.f;
      mix[0][j] += w0h * p; mix[1][j] += w1h * p; mix[2][j] += w2h * p;
      mix[3][j] += w3h * p; mix[4][j] += w4h * p; mix[5][j] += w5h * p;
    }
  }
#pragma unroll
  for (int o = 0; o < 6; ++o) {
    uint4 pk4;
    pk4.x = pk2(mix[o][0], mix[o][1]);
    pk4.y = pk2(mix[o][2], mix[o][3]);
    pk4.z = pk2(mix[o][4], mix[o][5]);
    pk4.w = pk2(mix[o][6], mix[o][7]);
    *(uint4*)&Qb[(((size_t)(b * 6 + o)) << 20) + (size_t)n * 1024 + m0] = pk4;
  }
}

// ---------------- K5: PV split-K z=4, XCD-swizzled 1D grid, 100% occupancy ----------------
// 3072 blocks: xcd = bid&7; chunk c = (bid>>7)*8 + xcd -> (bo,z); tile = (bid>>3)&15.
// 16 tiles sharing (bo,z) run consecutively on one XCD -> V-chunk (32 KB) L2-resident.
__global__ __launch_bounds__(256, 8) void k_pv(const u16* __restrict__ Qm,
                                               const u16* __restrict__ vT,
                                               float* __restrict__ Ug,
                                               float* __restrict__ stats) {
  __shared__ u16 SH[2 * 64 * 68];    // Am | Vm, stride 68; f32-reused in epilogue
  u16* Am = SH;
  u16* Vm = SH + 64 * 68;
  const int t = threadIdx.x;
  const int bid = blockIdx.x;
  const int xcd = bid & 7;
  const int slot = bid >> 3;         // 0..383 per xcd
  const int lc = slot >> 4;          // 0..23
  const int tile = slot & 15;
  const int c = lc * 8 + xcd;        // 0..191
  const int bo = c >> 2, z = c & 3;
  const int n0 = tile * 64;
  const int wave = t >> 6, lane = t & 63;
  const int fr = lane & 15, quad = lane >> 4;
  const int srow = t >> 3, smg8 = (t & 7) * 8;
  const u16* qp = Qm + ((size_t)bo << 20);
  const u16* vp = vT + ((size_t)bo << 16);
  const int mbase = z * 256;
  f32x4 acc[4] = {};
  float s1 = 0.f, s2 = 0.f;
  for (int mc = 0; mc < 4; ++mc) {
    const int m = mbase + mc * 64 + smg8;
    uint4 q0 = *(const uint4*)&qp[(size_t)(n0 + srow) * 1024 + m];
    uint4 q1 = *(const uint4*)&qp[(size_t)(n0 + 32 + srow) * 1024 + m];
    uint4 v0 = *(const uint4*)&vp[(size_t)srow * 1024 + m];
    uint4 v1 = *(const uint4*)&vp[(size_t)(32 + srow) * 1024 + m];
    __syncthreads();                 // prev MFMA readers done (loads overlap the wait)
    *(uint4*)&Am[srow * 68 + smg8] = q0;
    *(uint4*)&Am[(32 + srow) * 68 + smg8] = q1;
    *(uint4*)&Vm[srow * 68 + smg8] = v0;
    *(uint4*)&Vm[(32 + srow) * 68 + smg8] = v1;
    {
      float f[8];
      unpack8(q0, f);
#pragma unroll
      for (int j = 0; j < 8; ++j) { s1 += f[j]; s2 += f[j] * f[j]; }
      unpack8(q1, f);
#pragma unroll
      for (int j = 0; j < 8; ++j) { s1 += f[j]; s2 += f[j] * f[j]; }
    }
    __syncthreads();                 // staging visible
#pragma unroll
    for (int ks = 0; ks < 2; ++ks) {
      short8 a = *(const short8*)&Am[(wave * 16 + fr) * 68 + ks * 32 + quad * 8];
#pragma unroll
      for (int ni = 0; ni < 4; ++ni) {
        short8 bb = *(const short8*)&Vm[(ni * 16 + fr) * 68 + ks * 32 + quad * 8];
        acc[ni] = MFMA(a, bb, acc[ni]);
      }
    }
  }
  __syncthreads();                   // all MFMA done before LDS reuse
  // ---- epilogue: stage U tile (64 n x 64 d f32) then stream contiguously
  float* FS = (float*)SH;
#pragma unroll
  for (int ni = 0; ni < 4; ++ni)
#pragma unroll
    for (int r = 0; r < 4; ++r)
      FS[(wave * 16 + quad * 4 + r) * 64 + ni * 16 + fr] = acc[ni][r];
  __syncthreads();
  float* Up = Ug + (size_t)z * U_ELEMS + ((size_t)(bo * 1024 + n0)) * 64;
#pragma unroll
  for (int j = 0; j < 4; ++j) {
    int o = j * 1024 + t * 4;
    *(float4*)&Up[o] = *(const float4*)&FS[o];
  }
  for (int off = 32; off; off >>= 1) {
    s1 += __shfl_xor(s1, off, 64);
    s2 += __shfl_xor(s2, off, 64);
  }
  if (lane == 0) {
    atomicAdd(&stats[bo * 2 + 0], s1);
    atomicAdd(&stats[bo * 2 + 1], s2);
  }
}

// ---------------- K4: finalize GN constants ----------------
__global__ __launch_bounds__(256) void k_finalize(const float* __restrict__ stats,
                                                  const float* __restrict__ colsum,
                                                  const float* __restrict__ gn_w,
                                                  const float* __restrict__ gn_b,
                                                  float* __restrict__ addend,
                                                  float* __restrict__ alphaArr) {
  int gid = blockIdx.x * 256 + threadIdx.x;   // 0..3071
  int bo = gid >> 6, d = gid & 63;
  int o = bo % 6;
  float s1 = stats[bo * 2], s2 = stats[bo * 2 + 1];
  const float inv = 1.f / 1048576.f;
  float mu = s1 * inv;
  float var = s2 * inv - mu * mu;
  float alpha = gn_w[o] * rsqrtf(var + 1e-5f * 1048576.f);
  float beta = gn_b[o] - alpha * mu;
  addend[gid] = beta * colsum[gid];
  if (d == 0) alphaArr[bo] = alpha;
}

// ---------------- apply: o_tmp = alpha*(U0+U1+U2+U3) + addend ----------------
__global__ __launch_bounds__(256) void k_apply(const float* __restrict__ Ug,
                                               const float* __restrict__ alphaArr,
                                               const float* __restrict__ addend,
                                               u16* __restrict__ otmp) {
  int i = blockIdx.x * 256 + threadIdx.x;
  int e = i * 4;
  int d4 = e & 63;
  int n = (e >> 6) & 1023;
  int bo = e >> 16;
  float al = alphaArr[bo];
  const float* ap = &addend[bo * 64 + d4];
  float4 u0 = *(const float4*)&Ug[e];
  float4 u1 = *(const float4*)&Ug[U_ELEMS + e];
  float4 u2 = *(const float4*)&Ug[2 * U_ELEMS + e];
  float4 u3 = *(const float4*)&Ug[3 * U_ELEMS + e];
  float ux = (u0.x + u1.x) + (u2.x + u3.x);
  float uy = (u0.y + u1.y) + (u2.y + u3.y);
  float uz = (u0.z + u1.z) + (u2.z + u3.z);
  float uw = (u0.w + u1.w) + (u2.w + u3.w);
  int b = bo / 6, o = bo - b * 6;
  uint2 w;
  w.x = pk2(al * ux + ap[0], al * uy + ap[1]);
  w.y = pk2(al * uz + ap[2], al * uw + ap[3]);
  *(uint2*)&otmp[((size_t)(b * 1024 + n)) * 384 + o * 64 + d4] = w;
}

// ---------------- K6: out(F32) = o_tmp @ w_proj^T + b_proj (coalesced epilogue) ----------------
__global__ __launch_bounds__(256, 3) void k_proj(const u16* __restrict__ A,
                                                 const float* __restrict__ w,
                                                 const float* __restrict__ bias,
                                                 float* __restrict__ out) {
  __shared__ u16 SH[16384];
  u16* As = SH;
  u16* Bs = SH + 8192;
  const int t = threadIdx.x;
  const int m0 = blockIdx.x * 128;
  const int n0 = blockIdx.y * 128;
  const int wave = t >> 6, lane = t & 63;
  const int wm = (wave & 1) * 64, wn = (wave >> 1) * 64;
  const int fr = lane & 15;
  const int fk = (lane >> 4) * 8;
  f32x4 acc[4][4] = {};
  for (int k0 = 0; k0 < 384; k0 += 64) {
#pragma unroll
    for (int i = 0; i < 4; ++i) {
      int e = (i * 256 + t) * 8;
      int row = e >> 6, col = e & 63;
      *(uint4*)&As[e] = *(const uint4*)&A[(size_t)(m0 + row) * 384 + k0 + col];
      const float* wp = &w[(size_t)(n0 + row) * 384 + k0 + col];
      float4 b0 = *(const float4*)wp, b1 = *(const float4*)(wp + 4);
      uint4 bv; bv.x = pk2(b0.x, b0.y); bv.y = pk2(b0.z, b0.w);
      bv.z = pk2(b1.x, b1.y); bv.w = pk2(b1.z, b1.w);
      *(uint4*)&Bs[e] = bv;
    }
    __syncthreads();
#pragma unroll
    for (int ks = 0; ks < 2; ++ks) {
      const int ko = ks * 32 + fk;
      short8 a[4], b[4];
#pragma unroll
      for (int mi = 0; mi < 4; ++mi) a[mi] = *(const short8*)&As[(wm + mi * 16 + fr) * 64 + ko];
#pragma unroll
      for (int ni = 0; ni < 4; ++ni) b[ni] = *(const short8*)&Bs[(wn + ni * 16 + fr) * 64 + ko];
#pragma unroll
      for (int mi = 0; mi < 4; ++mi)
#pragma unroll
        for (int ni = 0; ni < 4; ++ni) acc[mi][ni] = MFMA(a[mi], b[ni], acc[mi][ni]);
    }
    __syncthreads();
  }
  // ---- epilogue: two half-tiles (32x64 f32 per wave) staged in LDS, full-line float4 stores
  float* FS = (float*)SH;                 // 8192 f32
  float* fst = &FS[wave * 2048];
  float bv[4];
#pragma unroll
  for (int ni = 0; ni < 4; ++ni) bv[ni] = bias[n0 + wn + ni * 16 + fr];
#pragma unroll
  for (int half = 0; half < 2; ++half) {
#pragma unroll
    for (int mi2 = 0; mi2 < 2; ++mi2) {
      int mi = half * 2 + mi2;
#pragma unroll
      for (int ni = 0; ni < 4; ++ni)
#pragma unroll
        for (int r = 0; r < 4; ++r)
          fst[(mi2 * 16 + (lane >> 4) * 4 + r) * 64 + ni * 16 + fr] = acc[mi][ni][r] + bv[ni];
    }
#pragma unroll
    for (int g = 0; g < 4; ++g)
#pragma unroll
      for (int i2 = 0; i2 < 2; ++i2) {
        int lrow = g * 8 + (lane >> 3);
        int colf = i2 * 32 + (lane & 7) * 4;
        float4 v = *(const float4*)&fst[lrow * 64 + colf];
        *(float4*)&out[(size_t)(m0 + wm + half * 32 + lrow) * 384 + n0 + wn + colf] = v;
      }
  }
}

extern "C" void kernel_launch(void* const* d_in, const int* in_sizes, int n_in,
                              void* d_out, int out_size, void* d_ws, size_t ws_size,
                              hipStream_t stream) {
  (void)in_sizes; (void)n_in; (void)out_size; (void)ws_size;
  const float* x      = (const float*)d_in[0];
  const float* w_qkv  = (const float*)d_in[1];
  const float* w_proj = (const float*)d_in[2];
  const float* b_proj = (const float*)d_in[3];
  const float* w_kq   = (const float*)d_in[4];
  // d_in[5] b_kq: constant per map -> softmax-invariant, unused
  const float* w_head = (const float*)d_in[6];
  // d_in[7] b_head: constant per (b,o) map -> cancelled by GroupNorm, unused
  const float* gn_w   = (const float*)d_in[8];
  const float* gn_b   = (const float*)d_in[9];

  char* ws = (char*)d_ws;
  u16*   qb      = (u16*)(ws + OFF_Q);
  u16*   kb      = (u16*)(ws + OFF_K);
  u16*   vT      = (u16*)(ws + OFF_VT);
  u16*   Sb      = (u16*)(ws + OFF_S);
  float* Ug      = (float*)(ws + OFF_UG);   // aliases S (dead after conv); [4] split-K partials
  u16*   Qm      = (u16*)(ws + OFF_QM);     // mixed maps, o-indexed
  u16*   otmp    = (u16*)(ws + OFF_OT);
  float* stats   = (float*)(ws + OFF_ST);
  float* colsum  = (float*)(ws + OFF_CS);
  float* addend  = (float*)(ws + OFF_AD);
  float* alphaA  = (float*)(ws + OFF_AL);

  hipMemsetAsync(stats, 0, 896 + 12288, stream);   // stats + colsum
  k_qkv<<<dim3(64, 9), 256, 0, stream>>>(x, w_qkv, qb, kb, vT, colsum);
  k_qk<<<dim3(8, 8, 48), 256, 0, stream>>>(qb, kb, Sb);
  k_conv_softmax_mix<<<dim3(512, 8), 256, 0, stream>>>(Sb, w_kq, w_head, Qm);
  k_pv<<<dim3(3072), 256, 0, stream>>>(Qm, vT, Ug, stats);
  k_finalize<<<dim3(12), 256, 0, stream>>>(stats, colsum, gn_w, gn_b, addend, alphaA);
  k_apply<<<dim3(3072), 256, 0, stream>>>(Ug, alphaA, addend, otmp);
  k_proj<<<dim3(64, 3), 256, 0, stream>>>(otmp, w_proj, b_proj, (float*)d_out);
}

// Round 7
// 349.416 us; speedup vs baseline: 1.2061x; 1.2061x over previous
//
#include <hip/hip_runtime.h>

typedef unsigned short u16;
typedef __attribute__((ext_vector_type(8))) short short8;
typedef __attribute__((ext_vector_type(4))) float f32x4;

#define MFMA(a, b, c) __builtin_amdgcn_mfma_f32_16x16x32_bf16((a), (b), (c), 0, 0, 0)

__device__ inline float bf2f(u16 u) {
  union { unsigned int i; float f; } w; w.i = ((unsigned int)u) << 16; return w.f;
}
__device__ inline u16 f2bf(float x) {
  union { float f; unsigned int i; } u; u.f = x;
  unsigned int r = u.i + 0x7fffu + ((u.i >> 16) & 1u);  // RNE
  return (u16)(r >> 16);
}
__device__ inline unsigned int pk2(float a, float b) {
  return (unsigned int)f2bf(a) | ((unsigned int)f2bf(b) << 16);
}
__device__ inline void unpack8(uint4 v, float* f) {
  union { unsigned int i; float g; } c;
  c.i = v.x << 16;          f[0] = c.g;
  c.i = v.x & 0xffff0000u;  f[1] = c.g;
  c.i = v.y << 16;          f[2] = c.g;
  c.i = v.y & 0xffff0000u;  f[3] = c.g;
  c.i = v.z << 16;          f[4] = c.g;
  c.i = v.z & 0xffff0000u;  f[5] = c.g;
  c.i = v.w << 16;          f[6] = c.g;
  c.i = v.w & 0xffff0000u;  f[7] = c.g;
}

// ---------------- workspace layout (bytes) ----------------
static const size_t SZ_QKV = (size_t)48 * 1024 * 64 * 2;     // 6,291,456
static const size_t SZ_MAP = (size_t)48 * 1024 * 1024 * 2;   // 100,663,296
static const size_t OFF_Q  = 0;
static const size_t OFF_K  = OFF_Q + SZ_QKV;
static const size_t OFF_VT = OFF_K + SZ_QKV;
static const size_t OFF_S  = OFF_VT + SZ_QKV;                // S bf16; DEAD after conv -> U aliases
static const size_t OFF_UG = OFF_S;                          // U f32 [48][1024][64] (aliases S)
static const size_t OFF_QM = OFF_S + SZ_MAP;                 // Qmix = mixed (N*P-1) bf16 [48 bo][1024][1024]
static const size_t OFF_OT = OFF_QM + SZ_MAP;                // o_tmp [B,N,C] bf16
static const size_t OFF_ST = OFF_OT + SZ_QKV;                // stats 48*2 f32
static const size_t OFF_CS = OFF_ST + 896;                   // colsum_v 48*64 f32
static const size_t OFF_AD = OFF_CS + 12288;                 // addend 48*64 f32
static const size_t OFF_AL = OFF_AD + 12288;                 // alpha 48 f32

// ---------------- K1: qkv = x @ w_qkv^T, scatter to q,k,vT + fused colsum ----------------
__global__ __launch_bounds__(256, 3) void k_qkv(const float* __restrict__ x,
                                                const float* __restrict__ w,
                                                u16* __restrict__ qb,
                                                u16* __restrict__ kb,
                                                u16* __restrict__ vT,
                                                float* __restrict__ colsum) {
  __shared__ u16 SH[16384];          // As | Bs ; reused as epilogue staging
  u16* As = SH;
  u16* Bs = SH + 8192;
  const int t = threadIdx.x;
  const int m0 = blockIdx.x * 128;
  const int n0 = blockIdx.y * 128;
  const int wave = t >> 6, lane = t & 63;
  const int wm = (wave & 1) * 64, wn = (wave >> 1) * 64;
  const int fr = lane & 15;
  const int fk = (lane >> 4) * 8;
  f32x4 acc[4][4] = {};
  for (int k0 = 0; k0 < 384; k0 += 64) {
#pragma unroll
    for (int i = 0; i < 4; ++i) {
      int e = (i * 256 + t) * 8;
      int row = e >> 6, col = e & 63;
      const float* xp = &x[(size_t)(m0 + row) * 384 + k0 + col];
      const float* wp = &w[(size_t)(n0 + row) * 384 + k0 + col];
      float4 a0 = *(const float4*)xp, a1 = *(const float4*)(xp + 4);
      uint4 av; av.x = pk2(a0.x, a0.y); av.y = pk2(a0.z, a0.w);
      av.z = pk2(a1.x, a1.y); av.w = pk2(a1.z, a1.w);
      *(uint4*)&As[e] = av;
      float4 b0 = *(const float4*)wp, b1 = *(const float4*)(wp + 4);
      uint4 bv; bv.x = pk2(b0.x, b0.y); bv.y = pk2(b0.z, b0.w);
      bv.z = pk2(b1.x, b1.y); bv.w = pk2(b1.z, b1.w);
      *(uint4*)&Bs[e] = bv;
    }
    __syncthreads();
#pragma unroll
    for (int ks = 0; ks < 2; ++ks) {
      const int ko = ks * 32 + fk;
      short8 a[4], b[4];
#pragma unroll
      for (int mi = 0; mi < 4; ++mi) a[mi] = *(const short8*)&As[(wm + mi * 16 + fr) * 64 + ko];
#pragma unroll
      for (int ni = 0; ni < 4; ++ni) b[ni] = *(const short8*)&Bs[(wn + ni * 16 + fr) * 64 + ko];
#pragma unroll
      for (int mi = 0; mi < 4; ++mi)
#pragma unroll
        for (int ni = 0; ni < 4; ++ni) acc[mi][ni] = MFMA(a[mi], b[ni], acc[mi][ni]);
    }
    __syncthreads();
  }
  // ---- epilogue: per-wave LDS transpose, then full-line uint4 stores
  u16* st = &SH[wave * 4096];
  const int gcb = n0 + wn;                 // 64-aligned -> single (s,h) per wave
  const int s = gcb / 384;
  const int remb = gcb - s * 384;
  const int h = remb >> 6;
#pragma unroll
  for (int mi = 0; mi < 4; ++mi)
#pragma unroll
    for (int ni = 0; ni < 4; ++ni)
#pragma unroll
      for (int r = 0; r < 4; ++r) {
        int rl = mi * 16 + (lane >> 4) * 4 + r;   // n-local 0..63
        int cl = ni * 16 + fr;                    // d-local 0..63
        u16 val = f2bf(acc[mi][ni][r]);
        if (s == 2) st[cl * 64 + rl] = val;       // transpose for vT
        else        st[rl * 64 + cl] = val;
      }
  const int gm0 = m0 + wm;                 // 64-aligned
  const int b_ = gm0 >> 10;
  const size_t base = (size_t)(b_ * 6 + h) << 16;
  const int nloc = gm0 & 1023;
  const int r8 = lane >> 3, c8 = (lane & 7) * 8;
#pragma unroll
  for (int i = 0; i < 8; ++i) {
    int lrow = i * 8 + r8;
    uint4 v = *(const uint4*)&st[lrow * 64 + c8];
    if (s == 0)      *(uint4*)&qb[base + (size_t)(nloc + lrow) * 64 + c8] = v;
    else if (s == 1) *(uint4*)&kb[base + (size_t)(nloc + lrow) * 64 + c8] = v;
    else             *(uint4*)&vT[base + (size_t)lrow * 1024 + nloc + c8] = v;
  }
  // ---- fused colsum: s==2 waves reduce their 64n x 64d v-tile over n
  if (s == 2) {
#pragma unroll
    for (int ni = 0; ni < 4; ++ni) {
      float p = 0.f;
#pragma unroll
      for (int mi = 0; mi < 4; ++mi)
#pragma unroll
        for (int r = 0; r < 4; ++r) p += bf2f(f2bf(acc[mi][ni][r]));
      p += __shfl_xor(p, 16, 64);
      p += __shfl_xor(p, 32, 64);
      if ((lane >> 4) == 0)
        atomicAdd(&colsum[(b_ * 6 + h) * 64 + ni * 16 + fr], p);
    }
  }
}

// ---------------- K2a: S = (q @ k^T) * SCALE (coalesced epilogue) ----------------
__global__ __launch_bounds__(256, 3) void k_qk(const u16* __restrict__ qb,
                                               const u16* __restrict__ kb,
                                               u16* __restrict__ S) {
  __shared__ u16 SH[16384];
  u16* As = SH;
  u16* Bs = SH + 8192;
  const int t = threadIdx.x;
  const int m0 = blockIdx.x * 128, n0 = blockIdx.y * 128;
  const int bh = blockIdx.z;
  const u16* A = qb + ((size_t)bh << 16);
  const u16* Bp = kb + ((size_t)bh << 16);
  const int wave = t >> 6, lane = t & 63;
  const int wm = (wave & 1) * 64, wn = (wave >> 1) * 64;
  const int fr = lane & 15;
  const int fk = (lane >> 4) * 8;
  f32x4 acc[4][4] = {};
#pragma unroll
  for (int i = 0; i < 4; ++i) {
    int e = (i * 256 + t) * 8;
    *(uint4*)&As[e] = *(const uint4*)&A[(size_t)m0 * 64 + e];
    *(uint4*)&Bs[e] = *(const uint4*)&Bp[(size_t)n0 * 64 + e];
  }
  __syncthreads();
#pragma unroll
  for (int ks = 0; ks < 2; ++ks) {
    const int ko = ks * 32 + fk;
    short8 a[4], b[4];
#pragma unroll
    for (int mi = 0; mi < 4; ++mi) a[mi] = *(const short8*)&As[(wm + mi * 16 + fr) * 64 + ko];
#pragma unroll
    for (int ni = 0; ni < 4; ++ni) b[ni] = *(const short8*)&Bs[(wn + ni * 16 + fr) * 64 + ko];
#pragma unroll
    for (int mi = 0; mi < 4; ++mi)
#pragma unroll
      for (int ni = 0; ni < 4; ++ni) acc[mi][ni] = MFMA(a[mi], b[ni], acc[mi][ni]);
  }
  __syncthreads();                        // all waves done reading As/Bs
  u16* st = &SH[wave * 4096];
#pragma unroll
  for (int mi = 0; mi < 4; ++mi)
#pragma unroll
    for (int ni = 0; ni < 4; ++ni)
#pragma unroll
      for (int r = 0; r < 4; ++r)
        st[(mi * 16 + (lane >> 4) * 4 + r) * 64 + ni * 16 + fr] = f2bf(acc[mi][ni][r] * 0.125f);
  const size_t sb = (size_t)bh << 20;
  const int grow0 = m0 + wm, gcol0 = n0 + wn;
  const int r8 = lane >> 3, c8 = (lane & 7) * 8;
#pragma unroll
  for (int i = 0; i < 8; ++i) {
    int lrow = i * 8 + r8;
    uint4 v = *(const uint4*)&st[lrow * 64 + c8];
    *(uint4*)&S[sb + (size_t)(grow0 + lrow) * 1024 + gcol0 + c8] = v;
  }
}

// ---------------- K2b: depthwise 3x3 conv + softmax + HEAD MIX ----------------
__global__ __launch_bounds__(256, 3) void k_conv_softmax_mix(const u16* __restrict__ S,
                                                             const float* __restrict__ w_kq,
                                                             const float* __restrict__ wh,
                                                             u16* __restrict__ Qb) {
  __shared__ u16 Sr[24 * 1040];      // [h*4 + i][1040], i = input row (n0-1+i)
  __shared__ float redA[4], redB[4];
  const int t = threadIdx.x;
  const int b = blockIdx.y;
  const int n0 = blockIdx.x * 2;
  if (t < 24) { Sr[t * 1040 + 7] = 0; Sr[t * 1040 + 1032] = 0; }
#pragma unroll
  for (int c = 0; c < 12; ++c) {
    int lid = c * 256 + t;           // 0..3071
    int hrow = lid >> 7;             // 0..23
    int col8 = (lid & 127) * 8;
    int h = hrow >> 2, i = hrow & 3;
    int g = n0 - 1 + i;
    uint4 val = make_uint4(0u, 0u, 0u, 0u);
    if (g >= 0 && g < 1024)
      val = *(const uint4*)&S[(((size_t)(b * 6 + h)) << 20) + (size_t)g * 1024 + col8];
    *(uint4*)&Sr[hrow * 1040 + 8 + col8] = val;
  }
  __syncthreads();
  const int row = t >> 7;            // 0..1 (output row within block)
  const int wave = t >> 6;
  const int lane = t & 63;
  const int m0 = (t & 127) * 8;
  const int n = n0 + row;
  float mix[6][8];
#pragma unroll
  for (int o = 0; o < 6; ++o)
#pragma unroll
    for (int j = 0; j < 8; ++j) mix[o][j] = 0.f;
  for (int h = 0; h < 6; ++h) {
    float wv[9];
#pragma unroll
    for (int i = 0; i < 9; ++i) wv[i] = w_kq[h * 9 + i];
    float o8[8] = {0.f, 0.f, 0.f, 0.f, 0.f, 0.f, 0.f, 0.f};
#pragma unroll
    for (int i = 0; i < 3; ++i) {
      const u16* rowp = &Sr[(h * 4 + row + i) * 1040 + 8];
      float left = bf2f(rowp[m0 - 1]);
      float md[8];
      unpack8(*(const uint4*)&rowp[m0], md);
      float right = bf2f(rowp[m0 + 8]);
      float w0 = wv[i * 3 + 0], w1 = wv[i * 3 + 1], w2 = wv[i * 3 + 2];
      o8[0] += w0 * left + w1 * md[0] + w2 * md[1];
#pragma unroll
      for (int j = 1; j < 7; ++j) o8[j] += w0 * md[j - 1] + w1 * md[j] + w2 * md[j + 1];
      o8[7] += w0 * md[6] + w1 * md[7] + w2 * right;
    }
    float mx = o8[0];
#pragma unroll
    for (int j = 1; j < 8; ++j) mx = fmaxf(mx, o8[j]);
    for (int off = 32; off; off >>= 1) mx = fmaxf(mx, __shfl_xor(mx, off, 64));
    if (lane == 0) redA[wave] = mx;
    __syncthreads();
    float rmax = fmaxf(redA[row * 2], redA[row * 2 + 1]);
    float e8[8], s = 0.f;
#pragma unroll
    for (int j = 0; j < 8; ++j) { e8[j] = __expf(o8[j] - rmax); s += e8[j]; }
    for (int off = 32; off; off >>= 1) s += __shfl_xor(s, off, 64);
    if (lane == 0) redB[wave] = s;
    __syncthreads();
    float rsum = redB[row * 2] + redB[row * 2 + 1];
    float scale = 1024.f / rsum;
    const float w0h = wh[0 * 6 + h], w1h = wh[1 * 6 + h], w2h = wh[2 * 6 + h],
                w3h = wh[3 * 6 + h], w4h = wh[4 * 6 + h], w5h = wh[5 * 6 + h];
#pragma unroll
    for (int j = 0; j < 8; ++j) {
      float p = e8[j] * scale - 1.f;
      mix[0][j] += w0h * p; mix[1][j] += w1h * p; mix[2][j] += w2h * p;
      mix[3][j] += w3h * p; mix[4][j] += w4h * p; mix[5][j] += w5h * p;
    }
  }
#pragma unroll
  for (int o = 0; o < 6; ++o) {
    uint4 pk4;
    pk4.x = pk2(mix[o][0], mix[o][1]);
    pk4.y = pk2(mix[o][2], mix[o][3]);
    pk4.z = pk2(mix[o][4], mix[o][5]);
    pk4.w = pk2(mix[o][6], mix[o][7]);
    *(uint4*)&Qb[(((size_t)(b * 6 + o)) << 20) + (size_t)n * 1024 + m0] = pk4;
  }
}

// ---------------- K5: PV, deep-MLP superchunks (3 chunks / 12 loads in flight) ----------------
// grid (16, 48), z=1. 16 m-chunks = 5 superchunks of 3 + 1 tail. LDS 52 KB triple-buffer.
__global__ __launch_bounds__(256) void k_pv(const u16* __restrict__ Qm,
                                            const u16* __restrict__ vT,
                                            float* __restrict__ Ug,
                                            float* __restrict__ stats) {
  __shared__ u16 SH[3 * 2 * 64 * 68];    // 52,224 B: [c]{Am,Vm}, stride 68
  const int t = threadIdx.x;
  const int n0 = blockIdx.x * 64;
  const int bo = blockIdx.y;
  const int wave = t >> 6, lane = t & 63;
  const int fr = lane & 15, quad = lane >> 4;
  const int srow = t >> 3, smg8 = (t & 7) * 8;
  const u16* qp = Qm + ((size_t)bo << 20);
  const u16* vp = vT + ((size_t)bo << 16);
  f32x4 acc[4] = {};
  float s1 = 0.f, s2 = 0.f;
  for (int sc = 0; sc < 6; ++sc) {
    uint4 q0[3], q1[3], v0[3], v1[3];
#pragma unroll
    for (int c = 0; c < 3; ++c) {
      int mc = sc * 3 + c;
      if (mc < 16) {
        const int m = mc * 64 + smg8;
        q0[c] = *(const uint4*)&qp[(size_t)(n0 + srow) * 1024 + m];
        q1[c] = *(const uint4*)&qp[(size_t)(n0 + 32 + srow) * 1024 + m];
        v0[c] = *(const uint4*)&vp[(size_t)srow * 1024 + m];
        v1[c] = *(const uint4*)&vp[(size_t)(32 + srow) * 1024 + m];
      }
    }
    __syncthreads();                 // prev superchunk's MFMA readers done
#pragma unroll
    for (int c = 0; c < 3; ++c) {
      int mc = sc * 3 + c;
      if (mc < 16) {
        u16* Am = SH + c * (2 * 64 * 68);
        u16* Vm = Am + 64 * 68;
        *(uint4*)&Am[srow * 68 + smg8] = q0[c];
        *(uint4*)&Am[(32 + srow) * 68 + smg8] = q1[c];
        *(uint4*)&Vm[srow * 68 + smg8] = v0[c];
        *(uint4*)&Vm[(32 + srow) * 68 + smg8] = v1[c];
        float f[8];
        unpack8(q0[c], f);
#pragma unroll
        for (int j = 0; j < 8; ++j) { s1 += f[j]; s2 += f[j] * f[j]; }
        unpack8(q1[c], f);
#pragma unroll
        for (int j = 0; j < 8; ++j) { s1 += f[j]; s2 += f[j] * f[j]; }
      }
    }
    __syncthreads();                 // staging visible
#pragma unroll
    for (int c = 0; c < 3; ++c) {
      int mc = sc * 3 + c;
      if (mc < 16) {
        const u16* Am = SH + c * (2 * 64 * 68);
        const u16* Vm = Am + 64 * 68;
#pragma unroll
        for (int ks = 0; ks < 2; ++ks) {
          short8 a = *(const short8*)&Am[(wave * 16 + fr) * 68 + ks * 32 + quad * 8];
#pragma unroll
          for (int ni = 0; ni < 4; ++ni) {
            short8 bb = *(const short8*)&Vm[(ni * 16 + fr) * 68 + ks * 32 + quad * 8];
            acc[ni] = MFMA(a, bb, acc[ni]);
          }
        }
      }
    }
  }
  __syncthreads();                   // all MFMA done before LDS reuse
  // ---- epilogue: stage U tile (64 n x 64 d f32) then stream contiguously
  float* FS = (float*)SH;
#pragma unroll
  for (int ni = 0; ni < 4; ++ni)
#pragma unroll
    for (int r = 0; r < 4; ++r)
      FS[(wave * 16 + quad * 4 + r) * 64 + ni * 16 + fr] = acc[ni][r];
  __syncthreads();
  float* Up = Ug + ((size_t)(bo * 1024 + n0)) * 64;
#pragma unroll
  for (int j = 0; j < 4; ++j) {
    int o = j * 1024 + t * 4;
    *(float4*)&Up[o] = *(const float4*)&FS[o];
  }
  for (int off = 32; off; off >>= 1) {
    s1 += __shfl_xor(s1, off, 64);
    s2 += __shfl_xor(s2, off, 64);
  }
  if (lane == 0) {
    atomicAdd(&stats[bo * 2 + 0], s1);
    atomicAdd(&stats[bo * 2 + 1], s2);
  }
}

// ---------------- K4: finalize GN constants ----------------
__global__ __launch_bounds__(256) void k_finalize(const float* __restrict__ stats,
                                                  const float* __restrict__ colsum,
                                                  const float* __restrict__ gn_w,
                                                  const float* __restrict__ gn_b,
                                                  float* __restrict__ addend,
                                                  float* __restrict__ alphaArr) {
  int gid = blockIdx.x * 256 + threadIdx.x;   // 0..3071
  int bo = gid >> 6, d = gid & 63;
  int o = bo % 6;
  float s1 = stats[bo * 2], s2 = stats[bo * 2 + 1];
  const float inv = 1.f / 1048576.f;
  float mu = s1 * inv;
  float var = s2 * inv - mu * mu;
  float alpha = gn_w[o] * rsqrtf(var + 1e-5f * 1048576.f);
  float beta = gn_b[o] - alpha * mu;
  addend[gid] = beta * colsum[gid];
  if (d == 0) alphaArr[bo] = alpha;
}

// ---------------- apply: o_tmp = alpha*U + addend ----------------
__global__ __launch_bounds__(256) void k_apply(const float* __restrict__ Ug,
                                               const float* __restrict__ alphaArr,
                                               const float* __restrict__ addend,
                                               u16* __restrict__ otmp) {
  int i = blockIdx.x * 256 + threadIdx.x;
  int e = i * 4;
  int d4 = e & 63;
  int n = (e >> 6) & 1023;
  int bo = e >> 16;
  float al = alphaArr[bo];
  const float* ap = &addend[bo * 64 + d4];
  float4 u = *(const float4*)&Ug[e];
  int b = bo / 6, o = bo - b * 6;
  uint2 w;
  w.x = pk2(al * u.x + ap[0], al * u.y + ap[1]);
  w.y = pk2(al * u.z + ap[2], al * u.w + ap[3]);
  *(uint2*)&otmp[((size_t)(b * 1024 + n)) * 384 + o * 64 + d4] = w;
}

// ---------------- K6: out(F32) = o_tmp @ w_proj^T + b_proj (coalesced epilogue) ----------------
__global__ __launch_bounds__(256, 3) void k_proj(const u16* __restrict__ A,
                                                 const float* __restrict__ w,
                                                 const float* __restrict__ bias,
                                                 float* __restrict__ out) {
  __shared__ u16 SH[16384];
  u16* As = SH;
  u16* Bs = SH + 8192;
  const int t = threadIdx.x;
  const int m0 = blockIdx.x * 128;
  const int n0 = blockIdx.y * 128;
  const int wave = t >> 6, lane = t & 63;
  const int wm = (wave & 1) * 64, wn = (wave >> 1) * 64;
  const int fr = lane & 15;
  const int fk = (lane >> 4) * 8;
  f32x4 acc[4][4] = {};
  for (int k0 = 0; k0 < 384; k0 += 64) {
#pragma unroll
    for (int i = 0; i < 4; ++i) {
      int e = (i * 256 + t) * 8;
      int row = e >> 6, col = e & 63;
      *(uint4*)&As[e] = *(const uint4*)&A[(size_t)(m0 + row) * 384 + k0 + col];
      const float* wp = &w[(size_t)(n0 + row) * 384 + k0 + col];
      float4 b0 = *(const float4*)wp, b1 = *(const float4*)(wp + 4);
      uint4 bv; bv.x = pk2(b0.x, b0.y); bv.y = pk2(b0.z, b0.w);
      bv.z = pk2(b1.x, b1.y); bv.w = pk2(b1.z, b1.w);
      *(uint4*)&Bs[e] = bv;
    }
    __syncthreads();
#pragma unroll
    for (int ks = 0; ks < 2; ++ks) {
      const int ko = ks * 32 + fk;
      short8 a[4], b[4];
#pragma unroll
      for (int mi = 0; mi < 4; ++mi) a[mi] = *(const short8*)&As[(wm + mi * 16 + fr) * 64 + ko];
#pragma unroll
      for (int ni = 0; ni < 4; ++ni) b[ni] = *(const short8*)&Bs[(wn + ni * 16 + fr) * 64 + ko];
#pragma unroll
      for (int mi = 0; mi < 4; ++mi)
#pragma unroll
        for (int ni = 0; ni < 4; ++ni) acc[mi][ni] = MFMA(a[mi], b[ni], acc[mi][ni]);
    }
    __syncthreads();
  }
  // ---- epilogue: two half-tiles (32x64 f32 per wave) staged in LDS, full-line float4 stores
  float* FS = (float*)SH;                 // 8192 f32
  float* fst = &FS[wave * 2048];
  float bv[4];
#pragma unroll
  for (int ni = 0; ni < 4; ++ni) bv[ni] = bias[n0 + wn + ni * 16 + fr];
#pragma unroll
  for (int half = 0; half < 2; ++half) {
#pragma unroll
    for (int mi2 = 0; mi2 < 2; ++mi2) {
      int mi = half * 2 + mi2;
#pragma unroll
      for (int ni = 0; ni < 4; ++ni)
#pragma unroll
        for (int r = 0; r < 4; ++r)
          fst[(mi2 * 16 + (lane >> 4) * 4 + r) * 64 + ni * 16 + fr] = acc[mi][ni][r] + bv[ni];
    }
#pragma unroll
    for (int g = 0; g < 4; ++g)
#pragma unroll
      for (int i2 = 0; i2 < 2; ++i2) {
        int lrow = g * 8 + (lane >> 3);
        int colf = i2 * 32 + (lane & 7) * 4;
        float4 v = *(const float4*)&fst[lrow * 64 + colf];
        *(float4*)&out[(size_t)(m0 + wm + half * 32 + lrow) * 384 + n0 + wn + colf] = v;
      }
  }
}

extern "C" void kernel_launch(void* const* d_in, const int* in_sizes, int n_in,
                              void* d_out, int out_size, void* d_ws, size_t ws_size,
                              hipStream_t stream) {
  (void)in_sizes; (void)n_in; (void)out_size; (void)ws_size;
  const float* x      = (const float*)d_in[0];
  const float* w_qkv  = (const float*)d_in[1];
  const float* w_proj = (const float*)d_in[2];
  const float* b_proj = (const float*)d_in[3];
  const float* w_kq   = (const float*)d_in[4];
  // d_in[5] b_kq: constant per map -> softmax-invariant, unused
  const float* w_head = (const float*)d_in[6];
  // d_in[7] b_head: constant per (b,o) map -> cancelled by GroupNorm, unused
  const float* gn_w   = (const float*)d_in[8];
  const float* gn_b   = (const float*)d_in[9];

  char* ws = (char*)d_ws;
  u16*   qb      = (u16*)(ws + OFF_Q);
  u16*   kb      = (u16*)(ws + OFF_K);
  u16*   vT      = (u16*)(ws + OFF_VT);
  u16*   Sb      = (u16*)(ws + OFF_S);
  float* Ug      = (float*)(ws + OFF_UG);   // aliases S (dead after conv)
  u16*   Qm      = (u16*)(ws + OFF_QM);     // mixed maps, o-indexed
  u16*   otmp    = (u16*)(ws + OFF_OT);
  float* stats   = (float*)(ws + OFF_ST);
  float* colsum  = (float*)(ws + OFF_CS);
  float* addend  = (float*)(ws + OFF_AD);
  float* alphaA  = (float*)(ws + OFF_AL);

  hipMemsetAsync(stats, 0, 896 + 12288, stream);   // stats + colsum
  k_qkv<<<dim3(64, 9), 256, 0, stream>>>(x, w_qkv, qb, kb, vT, colsum);
  k_qk<<<dim3(8, 8, 48), 256, 0, stream>>>(qb, kb, Sb);
  k_conv_softmax_mix<<<dim3(512, 8), 256, 0, stream>>>(Sb, w_kq, w_head, Qm);
  k_pv<<<dim3(16, 48), 256, 0, stream>>>(Qm, vT, Ug, stats);
  k_finalize<<<dim3(12), 256, 0, stream>>>(stats, colsum, gn_w, gn_b, addend, alphaA);
  k_apply<<<dim3(3072), 256, 0, stream>>>(Ug, alphaA, addend, otmp);
  k_proj<<<dim3(64, 3), 256, 0, stream>>>(otmp, w_proj, b_proj, (float*)d_out);
}

// Round 8
// 286.484 us; speedup vs baseline: 1.4710x; 1.2197x over previous
//
#include <hip/hip_runtime.h>

typedef unsigned short u16;
typedef __attribute__((ext_vector_type(8))) short short8;
typedef __attribute__((ext_vector_type(4))) float f32x4;

#define MFMA(a, b, c) __builtin_amdgcn_mfma_f32_16x16x32_bf16((a), (b), (c), 0, 0, 0)

__device__ inline float bf2f(u16 u) {
  union { unsigned int i; float f; } w; w.i = ((unsigned int)u) << 16; return w.f;
}
__device__ inline u16 f2bf(float x) {
  union { float f; unsigned int i; } u; u.f = x;
  unsigned int r = u.i + 0x7fffu + ((u.i >> 16) & 1u);  // RNE
  return (u16)(r >> 16);
}
__device__ inline unsigned int pk2(float a, float b) {
  return (unsigned int)f2bf(a) | ((unsigned int)f2bf(b) << 16);
}
__device__ inline void unpack8(uint4 v, float* f) {
  union { unsigned int i; float g; } c;
  c.i = v.x << 16;          f[0] = c.g;
  c.i = v.x & 0xffff0000u;  f[1] = c.g;
  c.i = v.y << 16;          f[2] = c.g;
  c.i = v.y & 0xffff0000u;  f[3] = c.g;
  c.i = v.z << 16;          f[4] = c.g;
  c.i = v.z & 0xffff0000u;  f[5] = c.g;
  c.i = v.w << 16;          f[6] = c.g;
  c.i = v.w & 0xffff0000u;  f[7] = c.g;
}

// ---------------- workspace layout (bytes) ----------------
static const size_t SZ_QKV = (size_t)48 * 1024 * 64 * 2;     // 6,291,456
static const size_t SZ_MAP = (size_t)48 * 1024 * 1024 * 2;   // 100,663,296
static const size_t OFF_Q  = 0;
static const size_t OFF_K  = OFF_Q + SZ_QKV;
static const size_t OFF_VT = OFF_K + SZ_QKV;
static const size_t OFF_S  = OFF_VT + SZ_QKV;                // S bf16; DEAD after conv -> U aliases
static const size_t OFF_UG = OFF_S;                          // U f32 [48][1024][64] (aliases S)
static const size_t OFF_QM = OFF_S + SZ_MAP;                 // Q = N*P-1 bf16 [48 bh][1024][1024]
static const size_t OFF_OT = OFF_QM + SZ_MAP;                // o_tmp [B,N,C] bf16
static const size_t OFF_ST = OFF_OT + SZ_QKV;                // stats 48*2 f32
static const size_t OFF_CS = OFF_ST + 896;                   // colsum_v 48*64 f32
static const size_t OFF_AD = OFF_CS + 12288;                 // addend 48*64 f32
static const size_t OFF_AL = OFF_AD + 12288;                 // alpha 48 f32

// ---------------- K1: qkv = x @ w_qkv^T, scatter to q,k,vT + fused colsum ----------------
__global__ __launch_bounds__(256, 3) void k_qkv(const float* __restrict__ x,
                                                const float* __restrict__ w,
                                                u16* __restrict__ qb,
                                                u16* __restrict__ kb,
                                                u16* __restrict__ vT,
                                                float* __restrict__ colsum) {
  __shared__ u16 SH[16384];          // As | Bs ; reused as epilogue staging
  u16* As = SH;
  u16* Bs = SH + 8192;
  const int t = threadIdx.x;
  const int m0 = blockIdx.x * 128;
  const int n0 = blockIdx.y * 128;
  const int wave = t >> 6, lane = t & 63;
  const int wm = (wave & 1) * 64, wn = (wave >> 1) * 64;
  const int fr = lane & 15;
  const int fk = (lane >> 4) * 8;
  f32x4 acc[4][4] = {};
  for (int k0 = 0; k0 < 384; k0 += 64) {
#pragma unroll
    for (int i = 0; i < 4; ++i) {
      int e = (i * 256 + t) * 8;
      int row = e >> 6, col = e & 63;
      const float* xp = &x[(size_t)(m0 + row) * 384 + k0 + col];
      const float* wp = &w[(size_t)(n0 + row) * 384 + k0 + col];
      float4 a0 = *(const float4*)xp, a1 = *(const float4*)(xp + 4);
      uint4 av; av.x = pk2(a0.x, a0.y); av.y = pk2(a0.z, a0.w);
      av.z = pk2(a1.x, a1.y); av.w = pk2(a1.z, a1.w);
      *(uint4*)&As[e] = av;
      float4 b0 = *(const float4*)wp, b1 = *(const float4*)(wp + 4);
      uint4 bv; bv.x = pk2(b0.x, b0.y); bv.y = pk2(b0.z, b0.w);
      bv.z = pk2(b1.x, b1.y); bv.w = pk2(b1.z, b1.w);
      *(uint4*)&Bs[e] = bv;
    }
    __syncthreads();
#pragma unroll
    for (int ks = 0; ks < 2; ++ks) {
      const int ko = ks * 32 + fk;
      short8 a[4], b[4];
#pragma unroll
      for (int mi = 0; mi < 4; ++mi) a[mi] = *(const short8*)&As[(wm + mi * 16 + fr) * 64 + ko];
#pragma unroll
      for (int ni = 0; ni < 4; ++ni) b[ni] = *(const short8*)&Bs[(wn + ni * 16 + fr) * 64 + ko];
#pragma unroll
      for (int mi = 0; mi < 4; ++mi)
#pragma unroll
        for (int ni = 0; ni < 4; ++ni) acc[mi][ni] = MFMA(a[mi], b[ni], acc[mi][ni]);
    }
    __syncthreads();
  }
  // ---- epilogue: per-wave LDS transpose, then full-line uint4 stores
  u16* st = &SH[wave * 4096];
  const int gcb = n0 + wn;                 // 64-aligned -> single (s,h) per wave
  const int s = gcb / 384;
  const int remb = gcb - s * 384;
  const int h = remb >> 6;
#pragma unroll
  for (int mi = 0; mi < 4; ++mi)
#pragma unroll
    for (int ni = 0; ni < 4; ++ni)
#pragma unroll
      for (int r = 0; r < 4; ++r) {
        int rl = mi * 16 + (lane >> 4) * 4 + r;   // n-local 0..63
        int cl = ni * 16 + fr;                    // d-local 0..63
        u16 val = f2bf(acc[mi][ni][r]);
        if (s == 2) st[cl * 64 + rl] = val;       // transpose for vT
        else        st[rl * 64 + cl] = val;
      }
  const int gm0 = m0 + wm;                 // 64-aligned
  const int b_ = gm0 >> 10;
  const size_t base = (size_t)(b_ * 6 + h) << 16;
  const int nloc = gm0 & 1023;
  const int r8 = lane >> 3, c8 = (lane & 7) * 8;
#pragma unroll
  for (int i = 0; i < 8; ++i) {
    int lrow = i * 8 + r8;
    uint4 v = *(const uint4*)&st[lrow * 64 + c8];
    if (s == 0)      *(uint4*)&qb[base + (size_t)(nloc + lrow) * 64 + c8] = v;
    else if (s == 1) *(uint4*)&kb[base + (size_t)(nloc + lrow) * 64 + c8] = v;
    else             *(uint4*)&vT[base + (size_t)lrow * 1024 + nloc + c8] = v;
  }
  // ---- fused colsum: s==2 waves reduce their 64n x 64d v-tile over n
  if (s == 2) {
#pragma unroll
    for (int ni = 0; ni < 4; ++ni) {
      float p = 0.f;
#pragma unroll
      for (int mi = 0; mi < 4; ++mi)
#pragma unroll
        for (int r = 0; r < 4; ++r) p += bf2f(f2bf(acc[mi][ni][r]));
      p += __shfl_xor(p, 16, 64);
      p += __shfl_xor(p, 32, 64);
      if ((lane >> 4) == 0)
        atomicAdd(&colsum[(b_ * 6 + h) * 64 + ni * 16 + fr], p);
    }
  }
}

// ---------------- K2a: S = (q @ k^T) * SCALE (coalesced epilogue) ----------------
__global__ __launch_bounds__(256, 3) void k_qk(const u16* __restrict__ qb,
                                               const u16* __restrict__ kb,
                                               u16* __restrict__ S) {
  __shared__ u16 SH[16384];
  u16* As = SH;
  u16* Bs = SH + 8192;
  const int t = threadIdx.x;
  const int m0 = blockIdx.x * 128, n0 = blockIdx.y * 128;
  const int bh = blockIdx.z;
  const u16* A = qb + ((size_t)bh << 16);
  const u16* Bp = kb + ((size_t)bh << 16);
  const int wave = t >> 6, lane = t & 63;
  const int wm = (wave & 1) * 64, wn = (wave >> 1) * 64;
  const int fr = lane & 15;
  const int fk = (lane >> 4) * 8;
  f32x4 acc[4][4] = {};
#pragma unroll
  for (int i = 0; i < 4; ++i) {
    int e = (i * 256 + t) * 8;
    *(uint4*)&As[e] = *(const uint4*)&A[(size_t)m0 * 64 + e];
    *(uint4*)&Bs[e] = *(const uint4*)&Bp[(size_t)n0 * 64 + e];
  }
  __syncthreads();
#pragma unroll
  for (int ks = 0; ks < 2; ++ks) {
    const int ko = ks * 32 + fk;
    short8 a[4], b[4];
#pragma unroll
    for (int mi = 0; mi < 4; ++mi) a[mi] = *(const short8*)&As[(wm + mi * 16 + fr) * 64 + ko];
#pragma unroll
    for (int ni = 0; ni < 4; ++ni) b[ni] = *(const short8*)&Bs[(wn + ni * 16 + fr) * 64 + ko];
#pragma unroll
    for (int mi = 0; mi < 4; ++mi)
#pragma unroll
      for (int ni = 0; ni < 4; ++ni) acc[mi][ni] = MFMA(a[mi], b[ni], acc[mi][ni]);
  }
  __syncthreads();                        // all waves done reading As/Bs
  u16* st = &SH[wave * 4096];
#pragma unroll
  for (int mi = 0; mi < 4; ++mi)
#pragma unroll
    for (int ni = 0; ni < 4; ++ni)
#pragma unroll
      for (int r = 0; r < 4; ++r)
        st[(mi * 16 + (lane >> 4) * 4 + r) * 64 + ni * 16 + fr] = f2bf(acc[mi][ni][r] * 0.125f);
  const size_t sb = (size_t)bh << 20;
  const int grow0 = m0 + wm, gcol0 = n0 + wn;
  const int r8 = lane >> 3, c8 = (lane & 7) * 8;
#pragma unroll
  for (int i = 0; i < 8; ++i) {
    int lrow = i * 8 + r8;
    uint4 v = *(const uint4*)&st[lrow * 64 + c8];
    *(uint4*)&S[sb + (size_t)(grow0 + lrow) * 1024 + gcol0 + c8] = v;
  }
}

// ---------------- K2b: depthwise 3x3 conv + softmax, Q = N*P - 1 (bf16), per (b,h) ----------------
__global__ __launch_bounds__(256) void k_conv_softmax(const u16* __restrict__ S,
                                                      const float* __restrict__ w_kq,
                                                      u16* __restrict__ Qb) {
  __shared__ u16 Sr[10 * 1040];
  __shared__ float red[4];
  const int t = threadIdx.x;
  const int bh = blockIdx.y;
  const int h = bh % 6;
  const int r0 = blockIdx.x * 8;
  const u16* Sp = S + ((size_t)bh << 20);
  float wv[9];
#pragma unroll
  for (int i = 0; i < 9; ++i) wv[i] = w_kq[h * 9 + i];
  if (t < 10) { Sr[t * 1040 + 7] = 0; Sr[t * 1040 + 1032] = 0; }
#pragma unroll
  for (int c = 0; c < 5; ++c) {
    int e = (c * 256 + t) * 8;
    int i = e >> 10, col = e & 1023;
    int g = r0 - 1 + i;
    uint4 val = make_uint4(0u, 0u, 0u, 0u);
    if (g >= 0 && g < 1024) val = *(const uint4*)&Sp[(size_t)g * 1024 + col];
    *(uint4*)&Sr[i * 1040 + 8 + col] = val;
  }
  __syncthreads();
  const int half = t >> 7;
  const int lane = t & 63;
  const int m0 = (t & 127) * 8;
  for (int pass = 0; pass < 4; ++pass) {
    int rr = pass * 2 + half;       // output row in block (0..7)
    float o8[8];
#pragma unroll
    for (int j = 0; j < 8; ++j) o8[j] = 0.f;
#pragma unroll
    for (int i = 0; i < 3; ++i) {
      const u16* rowp = &Sr[(rr + i) * 1040 + 8];
      float left = bf2f(rowp[m0 - 1]);
      float md[8];
      unpack8(*(const uint4*)&rowp[m0], md);
      float right = bf2f(rowp[m0 + 8]);
      float w0 = wv[i * 3 + 0], w1 = wv[i * 3 + 1], w2 = wv[i * 3 + 2];
      o8[0] += w0 * left + w1 * md[0] + w2 * md[1];
#pragma unroll
      for (int j = 1; j < 7; ++j) o8[j] += w0 * md[j - 1] + w1 * md[j] + w2 * md[j + 1];
      o8[7] += w0 * md[6] + w1 * md[7] + w2 * right;
    }
    float mx = o8[0];
#pragma unroll
    for (int j = 1; j < 8; ++j) mx = fmaxf(mx, o8[j]);
    for (int off = 32; off; off >>= 1) mx = fmaxf(mx, __shfl_xor(mx, off, 64));
    if (lane == 0) red[t >> 6] = mx;
    __syncthreads();
    float rmax = fmaxf(red[half * 2], red[half * 2 + 1]);
    __syncthreads();
    float e8[8], s = 0.f;
#pragma unroll
    for (int j = 0; j < 8; ++j) { e8[j] = __expf(o8[j] - rmax); s += e8[j]; }
    for (int off = 32; off; off >>= 1) s += __shfl_xor(s, off, 64);
    if (lane == 0) red[t >> 6] = s;
    __syncthreads();
    float rsum = red[half * 2] + red[half * 2 + 1];
    __syncthreads();
    float scale = 1024.f / rsum;
    unsigned int pk[4];
#pragma unroll
    for (int jj = 0; jj < 4; ++jj)
      pk[jj] = pk2(e8[2 * jj] * scale - 1.f, e8[2 * jj + 1] * scale - 1.f);
    int n = r0 + rr;
    *(uint4*)&Qb[((size_t)bh << 20) + (size_t)n * 1024 + m0] = make_uint4(pk[0], pk[1], pk[2], pk[3]);
  }
}

// ---------------- K5: PV (r8 geometry) + mix-on-the-fly + fused stats + reg prefetch ----------------
// grid (16, 48): 64-row n tiles, full m loop (16 chunks, 8 MFMA/wave/chunk). Single U (f32).
// r0-proven loop; NEW: LDS-staged coalesced U epilogue (kills 4.7x write amp).
__global__ __launch_bounds__(256) void k_pvmix(const u16* __restrict__ Qm,
                                               const u16* __restrict__ vT,
                                               const float* __restrict__ wh,
                                               float* __restrict__ Ug,
                                               float* __restrict__ stats) {
  __shared__ u16 SH[2 * 64 * 72];    // Am | Vm ; f32-reused in epilogue (16 KB < 18 KB)
  u16* Am = SH;
  u16* Vm = SH + 64 * 72;
  const int t = threadIdx.x;
  const int n0 = blockIdx.x * 64;
  const int bo = blockIdx.y;
  const int b_ = bo / 6, o = bo - b_ * 6;
  const int wave = t >> 6, lane = t & 63;
  const int fr = lane & 15, quad = lane >> 4;
  const int srow = t >> 3, smg8 = (t & 7) * 8;   // staging: rows srow, srow+32
  float wo[6];
#pragma unroll
  for (int hh = 0; hh < 6; ++hh) wo[hh] = wh[o * 6 + hh];
  const size_t qbase = ((size_t)(b_ * 6)) << 20;
  const u16* vp = vT + ((size_t)bo << 16);
  uint4 qpre[2][6];
  uint4 vpre[2];
  {
    const int m = smg8;
#pragma unroll
    for (int i = 0; i < 2; ++i)
#pragma unroll
      for (int hh = 0; hh < 6; ++hh)
        qpre[i][hh] = *(const uint4*)&Qm[qbase + (((size_t)hh) << 20) +
                                         (size_t)(n0 + i * 32 + srow) * 1024 + m];
    vpre[0] = *(const uint4*)&vp[(size_t)srow * 1024 + m];
    vpre[1] = *(const uint4*)&vp[(size_t)(32 + srow) * 1024 + m];
  }
  f32x4 acc[4] = {};
  float s1 = 0.f, s2 = 0.f;
  for (int mc = 0; mc < 16; ++mc) {
    __syncthreads();   // prev MFMA done reading Am/Vm
    // consume prefetched regs: mix + stats + stage
#pragma unroll
    for (int i = 0; i < 2; ++i) {
      float mix[8] = {0.f, 0.f, 0.f, 0.f, 0.f, 0.f, 0.f, 0.f};
#pragma unroll
      for (int hh = 0; hh < 6; ++hh) {
        float qf[8];
        unpack8(qpre[i][hh], qf);
        float w = wo[hh];
#pragma unroll
        for (int j = 0; j < 8; ++j) mix[j] += w * qf[j];
      }
#pragma unroll
      for (int j = 0; j < 8; ++j) { s1 += mix[j]; s2 += mix[j] * mix[j]; }
      uint4 pk4;
      pk4.x = pk2(mix[0], mix[1]); pk4.y = pk2(mix[2], mix[3]);
      pk4.z = pk2(mix[4], mix[5]); pk4.w = pk2(mix[6], mix[7]);
      *(uint4*)&Am[(i * 32 + srow) * 72 + smg8] = pk4;
    }
    *(uint4*)&Vm[srow * 72 + smg8] = vpre[0];
    *(uint4*)&Vm[(32 + srow) * 72 + smg8] = vpre[1];
    // prefetch next chunk (overlaps barrier + MFMA)
    if (mc < 15) {
      const int m = (mc + 1) * 64 + smg8;
#pragma unroll
      for (int i = 0; i < 2; ++i)
#pragma unroll
        for (int hh = 0; hh < 6; ++hh)
          qpre[i][hh] = *(const uint4*)&Qm[qbase + (((size_t)hh) << 20) +
                                           (size_t)(n0 + i * 32 + srow) * 1024 + m];
      vpre[0] = *(const uint4*)&vp[(size_t)srow * 1024 + m];
      vpre[1] = *(const uint4*)&vp[(size_t)(32 + srow) * 1024 + m];
    }
    __syncthreads();   // staging visible
#pragma unroll
    for (int ks = 0; ks < 2; ++ks) {
      short8 a = *(const short8*)&Am[(wave * 16 + fr) * 72 + ks * 32 + quad * 8];
#pragma unroll
      for (int ni = 0; ni < 4; ++ni) {
        short8 b = *(const short8*)&Vm[(ni * 16 + fr) * 72 + ks * 32 + quad * 8];
        acc[ni] = MFMA(a, b, acc[ni]);
      }
    }
  }
  __syncthreads();                   // all MFMA done before LDS reuse
  // ---- epilogue: stage U tile (64 n x 64 d f32) in LDS, stream contiguously
  float* FS = (float*)SH;
#pragma unroll
  for (int ni = 0; ni < 4; ++ni)
#pragma unroll
    for (int r = 0; r < 4; ++r)
      FS[(wave * 16 + quad * 4 + r) * 64 + ni * 16 + fr] = acc[ni][r];
  __syncthreads();
  float* Up = Ug + ((size_t)(bo * 1024 + n0)) * 64;
#pragma unroll
  for (int j = 0; j < 4; ++j) {
    int oo = j * 1024 + t * 4;
    *(float4*)&Up[oo] = *(const float4*)&FS[oo];
  }
  for (int off = 32; off; off >>= 1) {
    s1 += __shfl_xor(s1, off, 64);
    s2 += __shfl_xor(s2, off, 64);
  }
  if (lane == 0) {
    atomicAdd(&stats[bo * 2 + 0], s1);
    atomicAdd(&stats[bo * 2 + 1], s2);
  }
}

// ---------------- K4: finalize GN constants ----------------
__global__ __launch_bounds__(256) void k_finalize(const float* __restrict__ stats,
                                                  const float* __restrict__ colsum,
                                                  const float* __restrict__ gn_w,
                                                  const float* __restrict__ gn_b,
                                                  float* __restrict__ addend,
                                                  float* __restrict__ alphaArr) {
  int gid = blockIdx.x * 256 + threadIdx.x;   // 0..3071
  int bo = gid >> 6, d = gid & 63;
  int o = bo % 6;
  float s1 = stats[bo * 2], s2 = stats[bo * 2 + 1];
  const float inv = 1.f / 1048576.f;
  float mu = s1 * inv;
  float var = s2 * inv - mu * mu;
  float alpha = gn_w[o] * rsqrtf(var + 1e-5f * 1048576.f);
  float beta = gn_b[o] - alpha * mu;
  addend[gid] = beta * colsum[gid];
  if (d == 0) alphaArr[bo] = alpha;
}

// ---------------- apply: o_tmp = alpha*U + addend ----------------
__global__ __launch_bounds__(256) void k_apply(const float* __restrict__ Ug,
                                               const float* __restrict__ alphaArr,
                                               const float* __restrict__ addend,
                                               u16* __restrict__ otmp) {
  int i = blockIdx.x * 256 + threadIdx.x;
  int e = i * 4;
  int d4 = e & 63;
  int n = (e >> 6) & 1023;
  int bo = e >> 16;
  float al = alphaArr[bo];
  const float* ap = &addend[bo * 64 + d4];
  float4 u = *(const float4*)&Ug[e];
  int b = bo / 6, o = bo - b * 6;
  uint2 w;
  w.x = pk2(al * u.x + ap[0], al * u.y + ap[1]);
  w.y = pk2(al * u.z + ap[2], al * u.w + ap[3]);
  *(uint2*)&otmp[((size_t)(b * 1024 + n)) * 384 + o * 64 + d4] = w;
}

// ---------------- K6: out(F32) = o_tmp @ w_proj^T + b_proj (coalesced epilogue) ----------------
__global__ __launch_bounds__(256, 3) void k_proj(const u16* __restrict__ A,
                                                 const float* __restrict__ w,
                                                 const float* __restrict__ bias,
                                                 float* __restrict__ out) {
  __shared__ u16 SH[16384];
  u16* As = SH;
  u16* Bs = SH + 8192;
  const int t = threadIdx.x;
  const int m0 = blockIdx.x * 128;
  const int n0 = blockIdx.y * 128;
  const int wave = t >> 6, lane = t & 63;
  const int wm = (wave & 1) * 64, wn = (wave >> 1) * 64;
  const int fr = lane & 15;
  const int fk = (lane >> 4) * 8;
  f32x4 acc[4][4] = {};
  for (int k0 = 0; k0 < 384; k0 += 64) {
#pragma unroll
    for (int i = 0; i < 4; ++i) {
      int e = (i * 256 + t) * 8;
      int row = e >> 6, col = e & 63;
      *(uint4*)&As[e] = *(const uint4*)&A[(size_t)(m0 + row) * 384 + k0 + col];
      const float* wp = &w[(size_t)(n0 + row) * 384 + k0 + col];
      float4 b0 = *(const float4*)wp, b1 = *(const float4*)(wp + 4);
      uint4 bv; bv.x = pk2(b0.x, b0.y); bv.y = pk2(b0.z, b0.w);
      bv.z = pk2(b1.x, b1.y); bv.w = pk2(b1.z, b1.w);
      *(uint4*)&Bs[e] = bv;
    }
    __syncthreads();
#pragma unroll
    for (int ks = 0; ks < 2; ++ks) {
      const int ko = ks * 32 + fk;
      short8 a[4], b[4];
#pragma unroll
      for (int mi = 0; mi < 4; ++mi) a[mi] = *(const short8*)&As[(wm + mi * 16 + fr) * 64 + ko];
#pragma unroll
      for (int ni = 0; ni < 4; ++ni) b[ni] = *(const short8*)&Bs[(wn + ni * 16 + fr) * 64 + ko];
#pragma unroll
      for (int mi = 0; mi < 4; ++mi)
#pragma unroll
        for (int ni = 0; ni < 4; ++ni) acc[mi][ni] = MFMA(a[mi], b[ni], acc[mi][ni]);
    }
    __syncthreads();
  }
  // ---- epilogue: two half-tiles (32x64 f32 per wave) staged in LDS, full-line float4 stores
  float* FS = (float*)SH;                 // 8192 f32
  float* fst = &FS[wave * 2048];
  float bv[4];
#pragma unroll
  for (int ni = 0; ni < 4; ++ni) bv[ni] = bias[n0 + wn + ni * 16 + fr];
#pragma unroll
  for (int half = 0; half < 2; ++half) {
#pragma unroll
    for (int mi2 = 0; mi2 < 2; ++mi2) {
      int mi = half * 2 + mi2;
#pragma unroll
      for (int ni = 0; ni < 4; ++ni)
#pragma unroll
        for (int r = 0; r < 4; ++r)
          fst[(mi2 * 16 + (lane >> 4) * 4 + r) * 64 + ni * 16 + fr] = acc[mi][ni][r] + bv[ni];
    }
#pragma unroll
    for (int g = 0; g < 4; ++g)
#pragma unroll
      for (int i2 = 0; i2 < 2; ++i2) {
        int lrow = g * 8 + (lane >> 3);
        int colf = i2 * 32 + (lane & 7) * 4;
        float4 v = *(const float4*)&fst[lrow * 64 + colf];
        *(float4*)&out[(size_t)(m0 + wm + half * 32 + lrow) * 384 + n0 + wn + colf] = v;
      }
  }
}

extern "C" void kernel_launch(void* const* d_in, const int* in_sizes, int n_in,
                              void* d_out, int out_size, void* d_ws, size_t ws_size,
                              hipStream_t stream) {
  (void)in_sizes; (void)n_in; (void)out_size; (void)ws_size;
  const float* x      = (const float*)d_in[0];
  const float* w_qkv  = (const float*)d_in[1];
  const float* w_proj = (const float*)d_in[2];
  const float* b_proj = (const float*)d_in[3];
  const float* w_kq   = (const float*)d_in[4];
  // d_in[5] b_kq: constant per map -> softmax-invariant, unused
  const float* w_head = (const float*)d_in[6];
  // d_in[7] b_head: constant per (b,o) map -> cancelled by GroupNorm, unused
  const float* gn_w   = (const float*)d_in[8];
  const float* gn_b   = (const float*)d_in[9];

  char* ws = (char*)d_ws;
  u16*   qb      = (u16*)(ws + OFF_Q);
  u16*   kb      = (u16*)(ws + OFF_K);
  u16*   vT      = (u16*)(ws + OFF_VT);
  u16*   Sb      = (u16*)(ws + OFF_S);
  float* Ug      = (float*)(ws + OFF_UG);   // aliases S (dead after conv)
  u16*   Qm      = (u16*)(ws + OFF_QM);     // per-head N*P-1 maps
  u16*   otmp    = (u16*)(ws + OFF_OT);
  float* stats   = (float*)(ws + OFF_ST);
  float* colsum  = (float*)(ws + OFF_CS);
  float* addend  = (float*)(ws + OFF_AD);
  float* alphaA  = (float*)(ws + OFF_AL);

  hipMemsetAsync(stats, 0, 896 + 12288, stream);   // stats + colsum
  k_qkv<<<dim3(64, 9), 256, 0, stream>>>(x, w_qkv, qb, kb, vT, colsum);
  k_qk<<<dim3(8, 8, 48), 256, 0, stream>>>(qb, kb, Sb);
  k_conv_softmax<<<dim3(128, 48), 256, 0, stream>>>(Sb, w_kq, Qm);
  k_pvmix<<<dim3(16, 48), 256, 0, stream>>>(Qm, vT, w_head, Ug, stats);
  k_finalize<<<dim3(12), 256, 0, stream>>>(stats, colsum, gn_w, gn_b, addend, alphaA);
  k_apply<<<dim3(3072), 256, 0, stream>>>(Ug, alphaA, addend, otmp);
  k_proj<<<dim3(64, 3), 256, 0, stream>>>(otmp, w_proj, b_proj, (float*)d_out);
}